// Round 3
// baseline (186.720 us; speedup 1.0000x reference)
//
#include <hip/hip_runtime.h>

#define PI2 6.28318530717958647692f

// ===========================================================================
// Kernel 1: per (b,t) plane forward DFT restricted to kept modes.
// Conjugate symmetry: X real => A2[128-kx][w] = conj(A2[kx][w]), so phase 1
// computes only kx = 0..16 (17 rows). Phase 2 derives kxi>=16 by conjugation.
// Phase 1: thread = (w2 0..63, kxq 0..3); handles columns {2w2, 2w2+1} via
//   ONE float2 load per row (wave = 512B contiguous segment), radix-2 fold
//   over rows h / h+64. Unroll-by-2 with 2-deep prefetch (4 loads in flight).
//   Twiddle reads: 2 ds_read_b128 per h-iter per wave.
// Phase 2: thread = (kxi 0..31, t 0..7); ky = {t,t+8}; ky-twiddles held in
//   registers, advanced by complex step, exact refresh at w=32. No E2 table.
// A2t: [w][row 0..16, stride 18] f2 (18.4 KB). Tt: [h<64][slot<16] f2 (8 KB).
// Xf layout: [plane][kxi][ky][ri] (1024 dwords/plane). Scale 1/16384.
// ===========================================================================
__global__ __launch_bounds__(256, 4) void k_fwd(const float* __restrict__ X,
                                                float* __restrict__ Xf) {
  __shared__ __attribute__((aligned(16))) float A2t[128 * 18 * 2];  // 18.4 KB
  __shared__ __attribute__((aligned(16))) float Tt[64 * 16 * 2];    // 8 KB
  const int plane = blockIdx.x;
  const int tid = threadIdx.x;
  const float* Xp = X + (size_t)plane * (128 * 128);

  // ---- E1 table: Tt[h][slot]: slot0 -> kx=16, slot k -> kx=k (1..15) ----
  #pragma unroll
  for (int k = 0; k < 4; ++k) {
    int idx = tid + k * 256;              // 1024 entries
    int h = idx >> 4, slot = idx & 15;
    int kx = slot ? slot : 16;
    float ang = -PI2 * (float)((kx * h) & 127) / 128.f;
    float s_, c_;
    __sincosf(ang, &s_, &c_);
    Tt[idx * 2] = c_; Tt[idx * 2 + 1] = s_;
  }
  __syncthreads();

  // ---- phase 1 ----
  {
    const int w2 = tid & 63;
    const int kxq = tid >> 6;             // wave-uniform
    float ar[4][2], ai[4][2];             // [slot j][col 0/1]
    #pragma unroll
    for (int j = 0; j < 4; ++j) {
      ar[j][0] = 0.f; ar[j][1] = 0.f; ai[j][0] = 0.f; ai[j][1] = 0.f;
    }
    float dc0 = 0.f, dc1 = 0.f;
    const float* colp = Xp + 2 * w2;

    float2 t0 = *(const float2*)&colp[0];
    float2 b0 = *(const float2*)&colp[64 * 128];
    float2 t1 = *(const float2*)&colp[128];
    float2 b1 = *(const float2*)&colp[65 * 128];

    auto rowstep = [&](int hh, float2 tt, float2 bb) {
      float uex = tt.x + bb.x, uox = tt.x - bb.x;
      float uey = tt.y + bb.y, uoy = tt.y - bb.y;
      const float4* Trow = (const float4*)&Tt[hh * 32];
      float4 e01 = Trow[kxq * 2];         // slots 4q (even kx), 4q+1 (odd kx)
      float4 e23 = Trow[kxq * 2 + 1];     // slots 4q+2 (even),  4q+3 (odd)
      ar[0][0] = fmaf(uex, e01.x, ar[0][0]); ai[0][0] = fmaf(uex, e01.y, ai[0][0]);
      ar[0][1] = fmaf(uey, e01.x, ar[0][1]); ai[0][1] = fmaf(uey, e01.y, ai[0][1]);
      ar[1][0] = fmaf(uox, e01.z, ar[1][0]); ai[1][0] = fmaf(uox, e01.w, ai[1][0]);
      ar[1][1] = fmaf(uoy, e01.z, ar[1][1]); ai[1][1] = fmaf(uoy, e01.w, ai[1][1]);
      ar[2][0] = fmaf(uex, e23.x, ar[2][0]); ai[2][0] = fmaf(uex, e23.y, ai[2][0]);
      ar[2][1] = fmaf(uey, e23.x, ar[2][1]); ai[2][1] = fmaf(uey, e23.y, ai[2][1]);
      ar[3][0] = fmaf(uox, e23.z, ar[3][0]); ai[3][0] = fmaf(uox, e23.w, ai[3][0]);
      ar[3][1] = fmaf(uoy, e23.z, ar[3][1]); ai[3][1] = fmaf(uoy, e23.w, ai[3][1]);
      if (kxq == 0) { dc0 += uex; dc1 += uey; }   // wave-uniform branch
    };

    for (int h = 0; h < 64; h += 2) {
      float2 nt0 = make_float2(0.f, 0.f), nb0 = nt0, nt1 = nt0, nb1 = nt0;
      if (h < 62) {
        nt0 = *(const float2*)&colp[(h + 2) * 128];
        nb0 = *(const float2*)&colp[(h + 66) * 128];
        nt1 = *(const float2*)&colp[(h + 3) * 128];
        nb1 = *(const float2*)&colp[(h + 67) * 128];
      }
      rowstep(h, t0, b0);
      rowstep(h + 1, t1, b1);
      t0 = nt0; b0 = nb0; t1 = nt1; b1 = nb1;
    }

    #pragma unroll
    for (int j = 0; j < 4; ++j) {
      int s = kxq * 4 + j;
      int row = (s == 0) ? 16 : s;
      *(float2*)&A2t[((2 * w2) * 18 + row) * 2]     = make_float2(ar[j][0], ai[j][0]);
      *(float2*)&A2t[((2 * w2 + 1) * 18 + row) * 2] = make_float2(ar[j][1], ai[j][1]);
    }
    if (kxq == 0) {
      *(float2*)&A2t[((2 * w2) * 18) * 2]     = make_float2(dc0, 0.f);
      *(float2*)&A2t[((2 * w2 + 1) * 18) * 2] = make_float2(dc1, 0.f);
    }
  }
  __syncthreads();

  // ---- phase 2: thread = (kxi 0..31, t 0..7); ky = {t, t+8} ----
  {
    const int kxi = tid >> 3;
    const int t = tid & 7;
    const int row = (kxi < 16) ? kxi : (32 - kxi);
    const float csign = (kxi < 16) ? 1.f : -1.f;   // conj for kxi>=16
    const float s = (t & 1) ? -1.f : 1.f;          // (-1)^ky
    float s0r, s0i, s1r, s1i;
    __sincosf(-PI2 * (float)t / 128.f, &s0i, &s0r);
    __sincosf(-PI2 * (float)(t + 8) / 128.f, &s1i, &s1r);
    float r0 = 0.f, i0 = 0.f, r1 = 0.f, i1 = 0.f;
    float E0r = 1.f, E0i = 0.f, E1r = 1.f, E1i = 0.f;
    #pragma unroll
    for (int half = 0; half < 2; ++half) {
      if (half == 1) {   // exact refresh: e^{-i pi t/2} == e^{-i pi (t+8)/2}
        float c_, s_;
        __sincosf(-1.57079632679489662f * (float)t, &s_, &c_);
        E0r = c_; E0i = s_; E1r = c_; E1i = s_;
      }
      for (int w = half * 32; w < half * 32 + 32; ++w) {
        float2 a = *(const float2*)&A2t[(w * 18 + row) * 2];
        float2 b = *(const float2*)&A2t[((w + 64) * 18 + row) * 2];
        float ur = fmaf(s, b.x, a.x);
        float ui = csign * fmaf(s, b.y, a.y);
        r0 = fmaf(ur, E0r, r0); r0 = fmaf(-ui, E0i, r0);
        i0 = fmaf(ur, E0i, i0); i0 = fmaf(ui, E0r, i0);
        r1 = fmaf(ur, E1r, r1); r1 = fmaf(-ui, E1i, r1);
        i1 = fmaf(ur, E1i, i1); i1 = fmaf(ui, E1r, i1);
        float u0 = E0r * s0r - E0i * s0i; E0i = E0r * s0i + E0i * s0r; E0r = u0;
        float u1 = E1r * s1r - E1i * s1i; E1i = E1r * s1i + E1i * s1r; E1r = u1;
      }
    }
    const float sc = 1.f / 16384.f;
    float* base = Xf + (size_t)plane * 1024 + kxi * 32;
    *(float2*)&base[t * 2]       = make_float2(r0 * sc, i0 * sc);
    *(float2*)&base[(t + 8) * 2] = make_float2(r1 * sc, i1 * sc);
  }
}

// ===========================================================================
// Kernel 2: channel mix. block = (corner 2, x 16, cg 16, bh 2), c-tile 4.
// grid 1024, 4 blocks/CU. Each block handles 8 b (bh half), weights re-read
// 2x (cheap, +16 MB HBM). thread = (cs 2 [wave-uniform], bb 8, y 16); each
// thread computes 2 c. Staging via float4 global loads (8 per thread).
// Y[b][c][kxi][ky][ri], same layout as Xf.
// ===========================================================================
__global__ __launch_bounds__(256, 4) void k_mix(const float* __restrict__ Xf,
                                                const float* __restrict__ w0r,
                                                const float* __restrict__ w0i,
                                                const float* __restrict__ w1r,
                                                const float* __restrict__ w1i,
                                                float* __restrict__ Y) {
  __shared__ __attribute__((aligned(16))) float Wl[4 * 32 * 16 * 4]; // 32 KB
  const int bid = blockIdx.x;               // 0..1023
  const int c2 = bid >> 9;
  const int x  = (bid >> 5) & 15;
  const int cg = (bid >> 1) & 15;
  const int bh = bid & 1;
  const int c0 = cg * 4;
  const int kxi = c2 * 16 + x;
  const float* Wr_g = c2 ? w1r : w0r;
  const float* Wi_g = c2 ? w1i : w0i;
  const int tid = threadIdx.x;

  // stage: Wl f4[(c_*32 + t2)*16 + y] = (wr_e, wi_e, wr_o, wi_o) for
  // t = 2*t2 (e) / 2*t2+1 (o). 512 y4-quads, 2 per thread, float4 loads.
  #pragma unroll
  for (int q = 0; q < 2; ++q) {
    int lin = tid + q * 256;                // 0..511
    int y4 = lin & 3, t2 = (lin >> 2) & 31, c_ = lin >> 7;
    size_t gae = (((size_t)(c0 + c_) * 64 + 2 * t2) * 16 + x) * 16 + y4 * 4;
    size_t gao = gae + 256;                 // t -> t+1 : stride 16*16
    float4 wre = *(const float4*)&Wr_g[gae];
    float4 wie = *(const float4*)&Wi_g[gae];
    float4 wro = *(const float4*)&Wr_g[gao];
    float4 wio = *(const float4*)&Wi_g[gao];
    float* dst = &Wl[((c_ * 32 + t2) * 16 + y4 * 4) * 4];
    *(float4*)&dst[0]  = make_float4(wre.x, wie.x, wro.x, wio.x);
    *(float4*)&dst[4]  = make_float4(wre.y, wie.y, wro.y, wio.y);
    *(float4*)&dst[8]  = make_float4(wre.z, wie.z, wro.z, wio.z);
    *(float4*)&dst[12] = make_float4(wre.w, wie.w, wro.w, wio.w);
  }
  __syncthreads();

  const int cs = tid >> 7;                  // wave-uniform c-pair select
  const int bb = (tid >> 4) & 7;
  const int y  = tid & 15;
  const int b  = bh * 8 + bb;

  float aR[2] = {}, aI[2] = {};
  const float* xbase = Xf + ((size_t)b * 64) * 1024 + kxi * 32 + y * 2;
  for (int t8 = 0; t8 < 64; t8 += 8) {
    float2 xv[8];
    #pragma unroll
    for (int q = 0; q < 8; ++q)
      xv[q] = *(const float2*)&xbase[(size_t)(t8 + q) * 1024];
    #pragma unroll
    for (int p = 0; p < 4; ++p) {           // t2 pair index
      int t2 = (t8 >> 1) + p;
      float2 xe = xv[2 * p], xo = xv[2 * p + 1];
      #pragma unroll
      for (int cj = 0; cj < 2; ++cj) {
        float4 wv = *(const float4*)&Wl[(((cs * 2 + cj) * 32 + t2) * 16 + y) * 4];
        aR[cj] = fmaf(xe.x, wv.x, aR[cj]); aR[cj] = fmaf(-xe.y, wv.y, aR[cj]);
        aI[cj] = fmaf(xe.x, wv.y, aI[cj]); aI[cj] = fmaf(xe.y, wv.x, aI[cj]);
        aR[cj] = fmaf(xo.x, wv.z, aR[cj]); aR[cj] = fmaf(-xo.y, wv.w, aR[cj]);
        aI[cj] = fmaf(xo.x, wv.w, aI[cj]); aI[cj] = fmaf(xo.y, wv.z, aI[cj]);
      }
    }
  }
  #pragma unroll
  for (int cj = 0; cj < 2; ++cj) {
    size_t ya = ((size_t)(b * 64 + c0 + cs * 2 + cj)) * 1024 + kxi * 32 + y * 2;
    *(float2*)&Y[ya] = make_float2(aR[cj], aI[cj]);
  }
}

// ===========================================================================
// Kernel 3: per (b,c) plane inverse.  (unchanged from round 2)
// Phase A: thread = (g 0..3 ky-quad, h2 0..63); handles h in {h2, h2+64}
//   via sign (-1)^kx on the shared twiddle. Stores Mt f4-packed with XOR
//   swizzle: f4idx = h*8 + (j ^ (h&7))  (write-conflict-free).
// Phase B: thread = (hp 0..7, w2 0..31); 16 h each, outputs w2, w2+32,
//   w2+64, w2+96. The w2+32 twiddles are the i^k register rotation of w2's
//   C/S; the +64 fold uses ky parity.
// ===========================================================================
__global__ __launch_bounds__(256, 4) void k_inv(const float* __restrict__ Y,
                                                float* __restrict__ out) {
  __shared__ __attribute__((aligned(16))) float Yl[1024];
  __shared__ __attribute__((aligned(16))) float Mt[128 * 16 * 2];  // 16 KB
  const int plane = blockIdx.x;
  const int tid = threadIdx.x;
  *(float4*)&Yl[tid * 4] = *(const float4*)&Y[(size_t)plane * 1024 + tid * 4];
  __syncthreads();

  // ---- phase A ----
  {
    const int g = tid >> 6;          // ky quad: ky = 4g..4g+3 (wave-uniform)
    const int h2 = tid & 63;
    float zr[2][4] = {}, zi[2][4] = {};   // [h-sel][ky j]
    float uw, uwi;                   // U = e^{+2pi i h2/128}
    __sincosf(PI2 * (float)h2 / 128.f, &uwi, &uw);
    const float4* Yl4 = (const float4*)Yl;
    float Tr = 1.f, Ti = 0.f;
    #pragma unroll 2
    for (int kxi = 0; kxi < 16; ++kxi) {
      float sgn = (kxi & 1) ? -1.f : 1.f;    // (-1)^kx for h2+64
      #pragma unroll
      for (int q = 0; q < 2; ++q) {
        float4 p = Yl4[kxi * 8 + g * 2 + q];
        float cr0 = p.x * Tr - p.y * Ti, ci0 = p.x * Ti + p.y * Tr;
        float cr1 = p.z * Tr - p.w * Ti, ci1 = p.z * Ti + p.w * Tr;
        zr[0][2*q]   += cr0; zi[0][2*q]   += ci0;
        zr[0][2*q+1] += cr1; zi[0][2*q+1] += ci1;
        zr[1][2*q]   = fmaf(sgn, cr0, zr[1][2*q]);   zi[1][2*q]   = fmaf(sgn, ci0, zi[1][2*q]);
        zr[1][2*q+1] = fmaf(sgn, cr1, zr[1][2*q+1]); zi[1][2*q+1] = fmaf(sgn, ci1, zi[1][2*q+1]);
      }
      float nr = Tr * uw - Ti * uwi, ni = Tr * uwi + Ti * uw;
      Tr = nr; Ti = ni;
    }
    __sincosf(PI2 * (float)((112 * h2) & 127) / 128.f, &Ti, &Tr);
    #pragma unroll 2
    for (int kxi = 16; kxi < 32; ++kxi) {
      float sgn = (kxi & 1) ? -1.f : 1.f;
      #pragma unroll
      for (int q = 0; q < 2; ++q) {
        float4 p = Yl4[kxi * 8 + g * 2 + q];
        float cr0 = p.x * Tr - p.y * Ti, ci0 = p.x * Ti + p.y * Tr;
        float cr1 = p.z * Tr - p.w * Ti, ci1 = p.z * Ti + p.w * Tr;
        zr[0][2*q]   += cr0; zi[0][2*q]   += ci0;
        zr[0][2*q+1] += cr1; zi[0][2*q+1] += ci1;
        zr[1][2*q]   = fmaf(sgn, cr0, zr[1][2*q]);   zi[1][2*q]   = fmaf(sgn, ci0, zi[1][2*q]);
        zr[1][2*q+1] = fmaf(sgn, cr1, zr[1][2*q+1]); zi[1][2*q+1] = fmaf(sgn, ci1, zi[1][2*q+1]);
      }
      float nr = Tr * uw - Ti * uwi, ni = Tr * uwi + Ti * uw;
      Tr = nr; Ti = ni;
    }
    #pragma unroll
    for (int hs = 0; hs < 2; ++hs) {
      int h = h2 + hs * 64;
      #pragma unroll
      for (int q = 0; q < 2; ++q) {
        int ky0 = g * 4 + 2 * q;
        float f0 = (ky0 == 0) ? 1.f : 2.f;
        float4 v = make_float4(f0 * zr[hs][2*q],   -f0 * zi[hs][2*q],
                               2.f * zr[hs][2*q+1], -2.f * zi[hs][2*q+1]);
        int f4i = h * 8 + ((g * 2 + q) ^ (h & 7));
        *(float4*)&Mt[f4i * 4] = v;
      }
    }
  }
  __syncthreads();

  // ---- phase B ----
  {
    const int hp = tid >> 5;        // 0..7
    const int w2 = tid & 31;        // 0..31
    float C[16], S[16];
    {
      float cw, sw;
      __sincosf(PI2 * (float)w2 / 128.f, &sw, &cw);
      C[0] = 1.f; S[0] = 0.f;
      #pragma unroll
      for (int k = 1; k < 16; ++k) {
        C[k] = C[k - 1] * cw - S[k - 1] * sw;
        S[k] = C[k - 1] * sw + S[k - 1] * cw;
      }
    }
    float* op = out + (size_t)plane * (128 * 128);
    const float4* Mt4 = (const float4*)Mt;
    #pragma unroll 2
    for (int hj = 0; hj < 16; ++hj) {
      int h = hp * 16 + hj;
      float e = 0.f, o = 0.f, e2 = 0.f, o2 = 0.f;
      #pragma unroll
      for (int j = 0; j < 8; ++j) {
        float4 m = Mt4[h * 8 + (j ^ (h & 7))];   // (Mc,Ms) ky=2j | ky=2j+1
        int k0 = 2 * j, k1 = 2 * j + 1;
        e = fmaf(m.x, C[k0], e); e = fmaf(m.y, S[k0], e);
        o = fmaf(m.z, C[k1], o); o = fmaf(m.w, S[k1], o);
        // w2+32: cos(th+pi k/2), sin(th+pi k/2) rotations
        if ((k0 & 2) == 0) { e2 = fmaf(m.x, C[k0], e2); e2 = fmaf(m.y, S[k0], e2); }
        else               { e2 = fmaf(-m.x, C[k0], e2); e2 = fmaf(-m.y, S[k0], e2); }
        if ((k1 & 2) == 0) { o2 = fmaf(m.w, C[k1], o2); o2 = fmaf(-m.z, S[k1], o2); }
        else               { o2 = fmaf(-m.w, C[k1], o2); o2 = fmaf(m.z, S[k1], o2); }
      }
      op[h * 128 + w2]      = e + o;
      op[h * 128 + w2 + 64] = e - o;
      op[h * 128 + w2 + 32] = e2 + o2;
      op[h * 128 + w2 + 96] = e2 - o2;
    }
  }
}

extern "C" void kernel_launch(void* const* d_in, const int* in_sizes, int n_in,
                              void* d_out, int out_size, void* d_ws, size_t ws_size,
                              hipStream_t stream) {
  const float* X   = (const float*)d_in[0];
  const float* w0r = (const float*)d_in[1];
  const float* w0i = (const float*)d_in[2];
  const float* w1r = (const float*)d_in[3];
  const float* w1i = (const float*)d_in[4];
  float* outp = (float*)d_out;
  float* Xf = (float*)d_ws;                  // 4 MB
  float* Yw = (float*)d_ws + (1u << 20);     // 4 MB
  k_fwd<<<1024, 256, 0, stream>>>(X, Xf);
  k_mix<<<1024, 256, 0, stream>>>(Xf, w0r, w0i, w1r, w1i, Yw);
  k_inv<<<1024, 256, 0, stream>>>(Yw, outp);
}

// Round 4
// 170.644 us; speedup vs baseline: 1.0942x; 1.0942x over previous
//
#include <hip/hip_runtime.h>

#define PI2 6.28318530717958647692f

// ===========================================================================
// Kernel 1: per (b,t) plane forward DFT restricted to kept modes.
// Conjugate symmetry: X real => A2[128-kx][w] = conj(A2[kx][w]), so phase 1
// computes only kx = 0..16 (17 rows). Phase 2 derives kxi>=16 by conjugation.
// Phase 1: thread = (w2 0..63, kxq 0..3); handles columns {2w2, 2w2+1} via
//   ONE float2 load per row (wave = 512B contiguous segment), radix-2 fold
//   over rows h / h+64. Unroll-by-4, prefetch 4 rows ahead (8 f2 in flight).
//   Straight-line macro body, constant-indexed arrays ONLY (r3's lambda put
//   the accumulators in scratch: WRITE_SIZE 4 MB -> 49 MB; do not reintroduce).
// Phase 2: thread = (kxi 0..31, t 0..7); ky = {t,t+8}; ky-twiddles held in
//   registers, advanced by complex step, exact refresh at w=32. No E2 table.
// A2t: [w][row 0..16, stride 18] f2 (18.4 KB). Tt: [h<64][slot<16] f2 (8 KB).
// Xf layout: [plane][kxi][ky][ri] (1024 dwords/plane). Scale 1/16384.
// ===========================================================================
__global__ __launch_bounds__(256, 4) void k_fwd(const float* __restrict__ X,
                                                float* __restrict__ Xf) {
  __shared__ __attribute__((aligned(16))) float A2t[128 * 18 * 2];  // 18.4 KB
  __shared__ __attribute__((aligned(16))) float Tt[64 * 16 * 2];    // 8 KB
  const int plane = blockIdx.x;
  const int tid = threadIdx.x;
  const float* Xp = X + (size_t)plane * (128 * 128);

  // ---- E1 table: Tt[h][slot]: slot0 -> kx=16, slot k -> kx=k (1..15) ----
  #pragma unroll
  for (int k = 0; k < 4; ++k) {
    int idx = tid + k * 256;              // 1024 entries
    int h = idx >> 4, slot = idx & 15;
    int kx = slot ? slot : 16;
    float ang = -PI2 * (float)((kx * h) & 127) / 128.f;
    float s_, c_;
    __sincosf(ang, &s_, &c_);
    Tt[idx * 2] = c_; Tt[idx * 2 + 1] = s_;
  }
  __syncthreads();

  // ---- phase 1 ----
  {
    const int w2 = tid & 63;
    const int kxq = tid >> 6;             // wave-uniform
    float ar[4][2], ai[4][2];             // [slot j][col 0/1], const-indexed
    #pragma unroll
    for (int j = 0; j < 4; ++j) {
      ar[j][0] = 0.f; ar[j][1] = 0.f; ai[j][0] = 0.f; ai[j][1] = 0.f;
    }
    float dc0 = 0.f, dc1 = 0.f;
    const float* colp = Xp + 2 * w2;

#define ROWSTEP(HH, TT_, BB_) do {                                           \
    float uex_ = (TT_).x + (BB_).x, uox_ = (TT_).x - (BB_).x;                \
    float uey_ = (TT_).y + (BB_).y, uoy_ = (TT_).y - (BB_).y;                \
    const float4* Trow_ = (const float4*)&Tt[(HH) * 32];                     \
    float4 e01_ = Trow_[kxq * 2];        /* slots 4q (even kx), 4q+1 (odd) */\
    float4 e23_ = Trow_[kxq * 2 + 1];    /* slots 4q+2 (even), 4q+3 (odd) */ \
    ar[0][0] = fmaf(uex_, e01_.x, ar[0][0]); ai[0][0] = fmaf(uex_, e01_.y, ai[0][0]); \
    ar[0][1] = fmaf(uey_, e01_.x, ar[0][1]); ai[0][1] = fmaf(uey_, e01_.y, ai[0][1]); \
    ar[1][0] = fmaf(uox_, e01_.z, ar[1][0]); ai[1][0] = fmaf(uox_, e01_.w, ai[1][0]); \
    ar[1][1] = fmaf(uoy_, e01_.z, ar[1][1]); ai[1][1] = fmaf(uoy_, e01_.w, ai[1][1]); \
    ar[2][0] = fmaf(uex_, e23_.x, ar[2][0]); ai[2][0] = fmaf(uex_, e23_.y, ai[2][0]); \
    ar[2][1] = fmaf(uey_, e23_.x, ar[2][1]); ai[2][1] = fmaf(uey_, e23_.y, ai[2][1]); \
    ar[3][0] = fmaf(uox_, e23_.z, ar[3][0]); ai[3][0] = fmaf(uox_, e23_.w, ai[3][0]); \
    ar[3][1] = fmaf(uoy_, e23_.z, ar[3][1]); ai[3][1] = fmaf(uoy_, e23_.w, ai[3][1]); \
    if (kxq == 0) { dc0 += uex_; dc1 += uey_; }      /* wave-uniform */      \
  } while (0)

    float2 p0t = *(const float2*)&colp[0 * 128];
    float2 p0b = *(const float2*)&colp[64 * 128];
    float2 p1t = *(const float2*)&colp[1 * 128];
    float2 p1b = *(const float2*)&colp[65 * 128];
    float2 p2t = *(const float2*)&colp[2 * 128];
    float2 p2b = *(const float2*)&colp[66 * 128];
    float2 p3t = *(const float2*)&colp[3 * 128];
    float2 p3b = *(const float2*)&colp[67 * 128];

    for (int h = 0; h < 64; h += 4) {
      float2 n0t, n0b, n1t, n1b, n2t, n2b, n3t, n3b;
      if (h < 60) {
        n0t = *(const float2*)&colp[(h + 4) * 128];
        n0b = *(const float2*)&colp[(h + 68) * 128];
        n1t = *(const float2*)&colp[(h + 5) * 128];
        n1b = *(const float2*)&colp[(h + 69) * 128];
        n2t = *(const float2*)&colp[(h + 6) * 128];
        n2b = *(const float2*)&colp[(h + 70) * 128];
        n3t = *(const float2*)&colp[(h + 7) * 128];
        n3b = *(const float2*)&colp[(h + 71) * 128];
      } else {
        n0t = make_float2(0.f, 0.f); n0b = n0t; n1t = n0t; n1b = n0t;
        n2t = n0t; n2b = n0t; n3t = n0t; n3b = n0t;
      }
      ROWSTEP(h, p0t, p0b);
      ROWSTEP(h + 1, p1t, p1b);
      ROWSTEP(h + 2, p2t, p2b);
      ROWSTEP(h + 3, p3t, p3b);
      p0t = n0t; p0b = n0b; p1t = n1t; p1b = n1b;
      p2t = n2t; p2b = n2b; p3t = n3t; p3b = n3b;
    }
#undef ROWSTEP

    #pragma unroll
    for (int j = 0; j < 4; ++j) {
      int s = kxq * 4 + j;
      int row = (s == 0) ? 16 : s;
      *(float2*)&A2t[((2 * w2) * 18 + row) * 2]     = make_float2(ar[j][0], ai[j][0]);
      *(float2*)&A2t[((2 * w2 + 1) * 18 + row) * 2] = make_float2(ar[j][1], ai[j][1]);
    }
    if (kxq == 0) {
      *(float2*)&A2t[((2 * w2) * 18) * 2]     = make_float2(dc0, 0.f);
      *(float2*)&A2t[((2 * w2 + 1) * 18) * 2] = make_float2(dc1, 0.f);
    }
  }
  __syncthreads();

  // ---- phase 2: thread = (kxi 0..31, t 0..7); ky = {t, t+8} ----
  {
    const int kxi = tid >> 3;
    const int t = tid & 7;
    const int row = (kxi < 16) ? kxi : (32 - kxi);
    const float csign = (kxi < 16) ? 1.f : -1.f;   // conj for kxi>=16
    const float s = (t & 1) ? -1.f : 1.f;          // (-1)^ky
    float s0r, s0i, s1r, s1i;
    __sincosf(-PI2 * (float)t / 128.f, &s0i, &s0r);
    __sincosf(-PI2 * (float)(t + 8) / 128.f, &s1i, &s1r);
    float r0 = 0.f, i0 = 0.f, r1 = 0.f, i1 = 0.f;
    float E0r = 1.f, E0i = 0.f, E1r = 1.f, E1i = 0.f;
    #pragma unroll
    for (int half = 0; half < 2; ++half) {
      if (half == 1) {   // exact refresh: e^{-i pi t/2} == e^{-i pi (t+8)/2}
        float c_, s_;
        __sincosf(-1.57079632679489662f * (float)t, &s_, &c_);
        E0r = c_; E0i = s_; E1r = c_; E1i = s_;
      }
      for (int w = half * 32; w < half * 32 + 32; ++w) {
        float2 a = *(const float2*)&A2t[(w * 18 + row) * 2];
        float2 b = *(const float2*)&A2t[((w + 64) * 18 + row) * 2];
        float ur = fmaf(s, b.x, a.x);
        float ui = csign * fmaf(s, b.y, a.y);
        r0 = fmaf(ur, E0r, r0); r0 = fmaf(-ui, E0i, r0);
        i0 = fmaf(ur, E0i, i0); i0 = fmaf(ui, E0r, i0);
        r1 = fmaf(ur, E1r, r1); r1 = fmaf(-ui, E1i, r1);
        i1 = fmaf(ur, E1i, i1); i1 = fmaf(ui, E1r, i1);
        float u0 = E0r * s0r - E0i * s0i; E0i = E0r * s0i + E0i * s0r; E0r = u0;
        float u1 = E1r * s1r - E1i * s1i; E1i = E1r * s1i + E1i * s1r; E1r = u1;
      }
    }
    const float sc = 1.f / 16384.f;
    float* base = Xf + (size_t)plane * 1024 + kxi * 32;
    *(float2*)&base[t * 2]       = make_float2(r0 * sc, i0 * sc);
    *(float2*)&base[(t + 8) * 2] = make_float2(r1 * sc, i1 * sc);
  }
}

// ===========================================================================
// Kernel 2: channel mix. block = (corner 2, x 16, cg 16), c-tile of 4.
// grid 512. Weights packed (t even, t odd) per float4 -> b128 LDS reads.
// thread = (b 16, y 16). Y[b][c][kxi][ky][ri], same layout as Xf.
// (Reverted verbatim to the round-2 configuration measured in the 165.7 run.)
// ===========================================================================
__global__ __launch_bounds__(256, 2) void k_mix(const float* __restrict__ Xf,
                                                const float* __restrict__ w0r,
                                                const float* __restrict__ w0i,
                                                const float* __restrict__ w1r,
                                                const float* __restrict__ w1i,
                                                float* __restrict__ Y) {
  __shared__ __attribute__((aligned(16))) float Wl[4 * 32 * 16 * 4]; // 32 KB
  const int bid = blockIdx.x;               // 0..511
  const int c2 = bid >> 8;
  const int x  = (bid >> 4) & 15;
  const int cg = bid & 15;
  const int c0 = cg * 4;
  const int kxi = c2 * 16 + x;
  const float* Wr_g = c2 ? w1r : w0r;
  const float* Wi_g = c2 ? w1i : w0i;
  const int tid = threadIdx.x;
  const int b = tid >> 4;
  const int y = tid & 15;

  // stage: 4096 complex; Wl f4[(c*32 + t/2)*16 + y] = (wr_e, wi_e, wr_o, wi_o)
  #pragma unroll
  for (int k = 0; k < 16; ++k) {
    int idx = tid + k * 256;                // 0..4095
    int y_ = idx & 15, t_ = (idx >> 4) & 63, c_ = idx >> 10;
    size_t ga = (((size_t)(c0 + c_) * 64 + t_) * 16 + x) * 16 + y_;
    int f2i = ((c_ * 32 + (t_ >> 1)) * 16 + y_) * 2 + (t_ & 1);
    *(float2*)&Wl[f2i * 2] = make_float2(Wr_g[ga], Wi_g[ga]);
  }
  __syncthreads();

  float aR[4] = {}, aI[4] = {};
  const float* xbase = Xf + ((size_t)b * 64) * 1024 + kxi * 32 + y * 2;
  for (int t8 = 0; t8 < 64; t8 += 8) {
    float2 xv[8];
    #pragma unroll
    for (int q = 0; q < 8; ++q)
      xv[q] = *(const float2*)&xbase[(size_t)(t8 + q) * 1024];
    #pragma unroll
    for (int p = 0; p < 4; ++p) {           // t2 pair index
      int t2 = (t8 >> 1) + p;
      float2 xe = xv[2 * p], xo = xv[2 * p + 1];
      #pragma unroll
      for (int cj = 0; cj < 4; ++cj) {
        float4 wv = *(const float4*)&Wl[((cj * 32 + t2) * 16 + y) * 4];
        aR[cj] = fmaf(xe.x, wv.x, aR[cj]); aR[cj] = fmaf(-xe.y, wv.y, aR[cj]);
        aI[cj] = fmaf(xe.x, wv.y, aI[cj]); aI[cj] = fmaf(xe.y, wv.x, aI[cj]);
        aR[cj] = fmaf(xo.x, wv.z, aR[cj]); aR[cj] = fmaf(-xo.y, wv.w, aR[cj]);
        aI[cj] = fmaf(xo.x, wv.w, aI[cj]); aI[cj] = fmaf(xo.y, wv.z, aI[cj]);
      }
    }
  }
  #pragma unroll
  for (int cj = 0; cj < 4; ++cj) {
    size_t ya = ((size_t)(b * 64 + c0 + cj)) * 1024 + kxi * 32 + y * 2;
    *(float2*)&Y[ya] = make_float2(aR[cj], aI[cj]);
  }
}

// ===========================================================================
// Kernel 3: per (b,c) plane inverse.  (unchanged since round 2)
// Phase A: thread = (g 0..3 ky-quad, h2 0..63); handles h in {h2, h2+64}
//   via sign (-1)^kx on the shared twiddle. Stores Mt f4-packed with XOR
//   swizzle: f4idx = h*8 + (j ^ (h&7))  (write-conflict-free).
// Phase B: thread = (hp 0..7, w2 0..31); 16 h each, outputs w2, w2+32,
//   w2+64, w2+96. The w2+32 twiddles are the i^k register rotation of w2's
//   C/S; the +64 fold uses ky parity.
// ===========================================================================
__global__ __launch_bounds__(256, 4) void k_inv(const float* __restrict__ Y,
                                                float* __restrict__ out) {
  __shared__ __attribute__((aligned(16))) float Yl[1024];
  __shared__ __attribute__((aligned(16))) float Mt[128 * 16 * 2];  // 16 KB
  const int plane = blockIdx.x;
  const int tid = threadIdx.x;
  *(float4*)&Yl[tid * 4] = *(const float4*)&Y[(size_t)plane * 1024 + tid * 4];
  __syncthreads();

  // ---- phase A ----
  {
    const int g = tid >> 6;          // ky quad: ky = 4g..4g+3 (wave-uniform)
    const int h2 = tid & 63;
    float zr[2][4] = {}, zi[2][4] = {};   // [h-sel][ky j]
    float uw, uwi;                   // U = e^{+2pi i h2/128}
    __sincosf(PI2 * (float)h2 / 128.f, &uwi, &uw);
    const float4* Yl4 = (const float4*)Yl;
    float Tr = 1.f, Ti = 0.f;
    #pragma unroll 2
    for (int kxi = 0; kxi < 16; ++kxi) {
      float sgn = (kxi & 1) ? -1.f : 1.f;    // (-1)^kx for h2+64
      #pragma unroll
      for (int q = 0; q < 2; ++q) {
        float4 p = Yl4[kxi * 8 + g * 2 + q];
        float cr0 = p.x * Tr - p.y * Ti, ci0 = p.x * Ti + p.y * Tr;
        float cr1 = p.z * Tr - p.w * Ti, ci1 = p.z * Ti + p.w * Tr;
        zr[0][2*q]   += cr0; zi[0][2*q]   += ci0;
        zr[0][2*q+1] += cr1; zi[0][2*q+1] += ci1;
        zr[1][2*q]   = fmaf(sgn, cr0, zr[1][2*q]);   zi[1][2*q]   = fmaf(sgn, ci0, zi[1][2*q]);
        zr[1][2*q+1] = fmaf(sgn, cr1, zr[1][2*q+1]); zi[1][2*q+1] = fmaf(sgn, ci1, zi[1][2*q+1]);
      }
      float nr = Tr * uw - Ti * uwi, ni = Tr * uwi + Ti * uw;
      Tr = nr; Ti = ni;
    }
    __sincosf(PI2 * (float)((112 * h2) & 127) / 128.f, &Ti, &Tr);
    #pragma unroll 2
    for (int kxi = 16; kxi < 32; ++kxi) {
      float sgn = (kxi & 1) ? -1.f : 1.f;
      #pragma unroll
      for (int q = 0; q < 2; ++q) {
        float4 p = Yl4[kxi * 8 + g * 2 + q];
        float cr0 = p.x * Tr - p.y * Ti, ci0 = p.x * Ti + p.y * Tr;
        float cr1 = p.z * Tr - p.w * Ti, ci1 = p.z * Ti + p.w * Tr;
        zr[0][2*q]   += cr0; zi[0][2*q]   += ci0;
        zr[0][2*q+1] += cr1; zi[0][2*q+1] += ci1;
        zr[1][2*q]   = fmaf(sgn, cr0, zr[1][2*q]);   zi[1][2*q]   = fmaf(sgn, ci0, zi[1][2*q]);
        zr[1][2*q+1] = fmaf(sgn, cr1, zr[1][2*q+1]); zi[1][2*q+1] = fmaf(sgn, ci1, zi[1][2*q+1]);
      }
      float nr = Tr * uw - Ti * uwi, ni = Tr * uwi + Ti * uw;
      Tr = nr; Ti = ni;
    }
    #pragma unroll
    for (int hs = 0; hs < 2; ++hs) {
      int h = h2 + hs * 64;
      #pragma unroll
      for (int q = 0; q < 2; ++q) {
        int ky0 = g * 4 + 2 * q;
        float f0 = (ky0 == 0) ? 1.f : 2.f;
        float4 v = make_float4(f0 * zr[hs][2*q],   -f0 * zi[hs][2*q],
                               2.f * zr[hs][2*q+1], -2.f * zi[hs][2*q+1]);
        int f4i = h * 8 + ((g * 2 + q) ^ (h & 7));
        *(float4*)&Mt[f4i * 4] = v;
      }
    }
  }
  __syncthreads();

  // ---- phase B ----
  {
    const int hp = tid >> 5;        // 0..7
    const int w2 = tid & 31;        // 0..31
    float C[16], S[16];
    {
      float cw, sw;
      __sincosf(PI2 * (float)w2 / 128.f, &sw, &cw);
      C[0] = 1.f; S[0] = 0.f;
      #pragma unroll
      for (int k = 1; k < 16; ++k) {
        C[k] = C[k - 1] * cw - S[k - 1] * sw;
        S[k] = C[k - 1] * sw + S[k - 1] * cw;
      }
    }
    float* op = out + (size_t)plane * (128 * 128);
    const float4* Mt4 = (const float4*)Mt;
    #pragma unroll 2
    for (int hj = 0; hj < 16; ++hj) {
      int h = hp * 16 + hj;
      float e = 0.f, o = 0.f, e2 = 0.f, o2 = 0.f;
      #pragma unroll
      for (int j = 0; j < 8; ++j) {
        float4 m = Mt4[h * 8 + (j ^ (h & 7))];   // (Mc,Ms) ky=2j | ky=2j+1
        int k0 = 2 * j, k1 = 2 * j + 1;
        e = fmaf(m.x, C[k0], e); e = fmaf(m.y, S[k0], e);
        o = fmaf(m.z, C[k1], o); o = fmaf(m.w, S[k1], o);
        // w2+32: cos(th+pi k/2), sin(th+pi k/2) rotations
        if ((k0 & 2) == 0) { e2 = fmaf(m.x, C[k0], e2); e2 = fmaf(m.y, S[k0], e2); }
        else               { e2 = fmaf(-m.x, C[k0], e2); e2 = fmaf(-m.y, S[k0], e2); }
        if ((k1 & 2) == 0) { o2 = fmaf(m.w, C[k1], o2); o2 = fmaf(-m.z, S[k1], o2); }
        else               { o2 = fmaf(-m.w, C[k1], o2); o2 = fmaf(m.z, S[k1], o2); }
      }
      op[h * 128 + w2]      = e + o;
      op[h * 128 + w2 + 64] = e - o;
      op[h * 128 + w2 + 32] = e2 + o2;
      op[h * 128 + w2 + 96] = e2 - o2;
    }
  }
}

extern "C" void kernel_launch(void* const* d_in, const int* in_sizes, int n_in,
                              void* d_out, int out_size, void* d_ws, size_t ws_size,
                              hipStream_t stream) {
  const float* X   = (const float*)d_in[0];
  const float* w0r = (const float*)d_in[1];
  const float* w0i = (const float*)d_in[2];
  const float* w1r = (const float*)d_in[3];
  const float* w1i = (const float*)d_in[4];
  float* outp = (float*)d_out;
  float* Xf = (float*)d_ws;                  // 4 MB
  float* Yw = (float*)d_ws + (1u << 20);     // 4 MB
  k_fwd<<<1024, 256, 0, stream>>>(X, Xf);
  k_mix<<<512, 256, 0, stream>>>(Xf, w0r, w0i, w1r, w1i, Yw);
  k_inv<<<1024, 256, 0, stream>>>(Yw, outp);
}

// Round 5
// 160.955 us; speedup vs baseline: 1.1601x; 1.0602x over previous
//
#include <hip/hip_runtime.h>

#define PI2 6.28318530717958647692f

// ===========================================================================
// Kernel 1: per (b,t) plane forward DFT restricted to kept modes.
// Conjugate symmetry: X real => A2[128-kx][w] = conj(A2[kx][w]): phase 1
// computes kx = 0..16 only; phase 2 derives kxi>=16 by conjugation.
// Phase 1 (LDS-staged X, NEW): block streams its plane through LDS in 16
//   chunks of 8 rows (4 top rows 4c..4c+3 + their fold partners +64).
//   Reg-staged double buffer: load chunk c+1 (float4/thread, coalesced)
//   -> compute chunk c from LDS -> ds_write_b128 -> __syncthreads().
//   Removes the 4x redundant plane reads (each wave previously streamed all
//   128 columns itself) and the 1-deep per-thread global latency chain that
//   pinned k_fwd at ~44us across r0/r1/r4 variants.
//   thread = (w2 0..63, kxq 0..3): cols {2w2,2w2+1}, kx slot group kxq
//   (slot0 = kx16, slot k = kx k; kxq0 also accumulates DC kx=0).
// Phase 2: thread = (kxi 0..31, t 0..7); ky = {t,t+8}; ky-twiddles in
//   registers, advanced by complex step, exact refresh at w=32. No E2 table.
// A2t layout (NEW): row-major [kx 0..16][col f2, pad 134]. Writes are b128
//   at 16B/lane stride (conflict-free; r4's b64 stride-72 was 16-way =
//   417K conflicts). Reads: 17 rows x pad-134 -> 8 bank groups, ~2-way.
// LDS: A2 18.2K + Tt 8K + Xc 8K = 34.4 KB -> 4 blocks/CU.
// Xf layout: [plane][kxi][ky][ri] (1024 dwords/plane). Scale 1/16384.
// ===========================================================================
__global__ __launch_bounds__(256, 4) void k_fwd(const float* __restrict__ X,
                                                float* __restrict__ Xf) {
  __shared__ __attribute__((aligned(16))) float A2t[17 * 134 * 2];  // 18.2 KB
  __shared__ __attribute__((aligned(16))) float Tt[64 * 16 * 2];    // 8 KB
  __shared__ __attribute__((aligned(16))) float Xc[2][8 * 128];     // 8 KB
  const int plane = blockIdx.x;
  const int tid = threadIdx.x;
  const float* Xp = X + (size_t)plane * (128 * 128);

  // ---- E1 table: Tt[h][slot]: slot0 -> kx=16, slot k -> kx=k (1..15) ----
  #pragma unroll
  for (int k = 0; k < 4; ++k) {
    int idx = tid + k * 256;              // 1024 entries
    int h = idx >> 4, slot = idx & 15;
    int kx = slot ? slot : 16;
    float ang = -PI2 * (float)((kx * h) & 127) / 128.f;
    float s_, c_;
    __sincosf(ang, &s_, &c_);
    Tt[idx * 2] = c_; Tt[idx * 2 + 1] = s_;
  }

  // ---- phase 1 ----
  {
    const int w2 = tid & 63;
    const int kxq = tid >> 6;             // wave-uniform
    // loader mapping: thread -> 16B of the 4KB chunk
    const int lrow = tid >> 5;            // 0..7 (0-3 top, 4-7 bottom)
    const int lcol = (tid & 31) * 4;      // 0..124
    float ar[4][2], ai[4][2];             // [slot j][col 0/1], const-indexed
    #pragma unroll
    for (int j = 0; j < 4; ++j) {
      ar[j][0] = 0.f; ar[j][1] = 0.f; ai[j][0] = 0.f; ai[j][1] = 0.f;
    }
    float dc0 = 0.f, dc1 = 0.f;

    // prologue: chunk 0 -> buf 0 (also covers the E1-table barrier)
    {
      int rg = (lrow < 4) ? lrow : (60 + lrow);   // rows 0..3 / 64..67
      float4 v = *(const float4*)&Xp[rg * 128 + lcol];
      *(float4*)&Xc[0][lrow * 128 + lcol] = v;
    }
    __syncthreads();

#define ROWSTEP(HH, JJ, XB) do {                                             \
    float2 tt_ = *(const float2*)&(XB)[(JJ) * 128 + 2 * w2];                 \
    float2 bb_ = *(const float2*)&(XB)[((JJ) + 4) * 128 + 2 * w2];           \
    float uex_ = tt_.x + bb_.x, uox_ = tt_.x - bb_.x;                        \
    float uey_ = tt_.y + bb_.y, uoy_ = tt_.y - bb_.y;                        \
    const float4* Trow_ = (const float4*)&Tt[(HH) * 32];                     \
    float4 e01_ = Trow_[kxq * 2];        /* slots 4q (even kx), 4q+1 (odd) */\
    float4 e23_ = Trow_[kxq * 2 + 1];    /* slots 4q+2 (even), 4q+3 (odd) */ \
    ar[0][0] = fmaf(uex_, e01_.x, ar[0][0]); ai[0][0] = fmaf(uex_, e01_.y, ai[0][0]); \
    ar[0][1] = fmaf(uey_, e01_.x, ar[0][1]); ai[0][1] = fmaf(uey_, e01_.y, ai[0][1]); \
    ar[1][0] = fmaf(uox_, e01_.z, ar[1][0]); ai[1][0] = fmaf(uox_, e01_.w, ai[1][0]); \
    ar[1][1] = fmaf(uoy_, e01_.z, ar[1][1]); ai[1][1] = fmaf(uoy_, e01_.w, ai[1][1]); \
    ar[2][0] = fmaf(uex_, e23_.x, ar[2][0]); ai[2][0] = fmaf(uex_, e23_.y, ai[2][0]); \
    ar[2][1] = fmaf(uey_, e23_.x, ar[2][1]); ai[2][1] = fmaf(uey_, e23_.y, ai[2][1]); \
    ar[3][0] = fmaf(uox_, e23_.z, ar[3][0]); ai[3][0] = fmaf(uox_, e23_.w, ai[3][0]); \
    ar[3][1] = fmaf(uoy_, e23_.z, ar[3][1]); ai[3][1] = fmaf(uoy_, e23_.w, ai[3][1]); \
    if (kxq == 0) { dc0 += uex_; dc1 += uey_; }      /* wave-uniform */      \
  } while (0)

    for (int c = 0; c < 16; ++c) {
      // issue next chunk's load early (consumed after compute, ~200cy cover)
      float4 nv;
      if (c < 15) {
        int rg = (lrow < 4) ? (4 * (c + 1) + lrow) : (60 + 4 * (c + 1) + lrow);
        nv = *(const float4*)&Xp[rg * 128 + lcol];
      }
      const float* Xb = &Xc[c & 1][0];
      ROWSTEP(4 * c,     0, Xb);
      ROWSTEP(4 * c + 1, 1, Xb);
      ROWSTEP(4 * c + 2, 2, Xb);
      ROWSTEP(4 * c + 3, 3, Xb);
      if (c < 15)
        *(float4*)&Xc[(c + 1) & 1][lrow * 128 + lcol] = nv;
      __syncthreads();   // all reads of buf c done; chunk c+1 visible
    }
#undef ROWSTEP

    // A2 store: b128 at 16B/lane stride (conflict-free). row = kx.
    #pragma unroll
    for (int j = 0; j < 4; ++j) {
      int s = kxq * 4 + j;
      int row = (s == 0) ? 16 : s;
      *(float4*)&A2t[(row * 134 + 2 * w2) * 2] =
          make_float4(ar[j][0], ai[j][0], ar[j][1], ai[j][1]);
    }
    if (kxq == 0) {
      *(float4*)&A2t[(2 * w2) * 2] = make_float4(dc0, 0.f, dc1, 0.f);  // kx=0
    }
  }
  __syncthreads();

  // ---- phase 2: thread = (kxi 0..31, t 0..7); ky = {t, t+8} ----
  {
    const int kxi = tid >> 3;
    const int t = tid & 7;
    const int row = (kxi < 16) ? kxi : (32 - kxi);
    const float csign = (kxi < 16) ? 1.f : -1.f;   // conj for kxi>=16
    const float s = (t & 1) ? -1.f : 1.f;          // (-1)^ky
    float s0r, s0i, s1r, s1i;
    __sincosf(-PI2 * (float)t / 128.f, &s0i, &s0r);
    __sincosf(-PI2 * (float)(t + 8) / 128.f, &s1i, &s1r);
    float r0 = 0.f, i0 = 0.f, r1 = 0.f, i1 = 0.f;
    float E0r = 1.f, E0i = 0.f, E1r = 1.f, E1i = 0.f;
    #pragma unroll
    for (int half = 0; half < 2; ++half) {
      if (half == 1) {   // exact refresh: e^{-i pi t/2} == e^{-i pi (t+8)/2}
        float c_, s_;
        __sincosf(-1.57079632679489662f * (float)t, &s_, &c_);
        E0r = c_; E0i = s_; E1r = c_; E1i = s_;
      }
      for (int w = half * 32; w < half * 32 + 32; ++w) {
        float2 a = *(const float2*)&A2t[(row * 134 + w) * 2];
        float2 b = *(const float2*)&A2t[(row * 134 + w + 64) * 2];
        float ur = fmaf(s, b.x, a.x);
        float ui = csign * fmaf(s, b.y, a.y);
        r0 = fmaf(ur, E0r, r0); r0 = fmaf(-ui, E0i, r0);
        i0 = fmaf(ur, E0i, i0); i0 = fmaf(ui, E0r, i0);
        r1 = fmaf(ur, E1r, r1); r1 = fmaf(-ui, E1i, r1);
        i1 = fmaf(ur, E1i, i1); i1 = fmaf(ui, E1r, i1);
        float u0 = E0r * s0r - E0i * s0i; E0i = E0r * s0i + E0i * s0r; E0r = u0;
        float u1 = E1r * s1r - E1i * s1i; E1i = E1r * s1i + E1i * s1r; E1r = u1;
      }
    }
    const float sc = 1.f / 16384.f;
    float* base = Xf + (size_t)plane * 1024 + kxi * 32;
    *(float2*)&base[t * 2]       = make_float2(r0 * sc, i0 * sc);
    *(float2*)&base[(t + 8) * 2] = make_float2(r1 * sc, i1 * sc);
  }
}

// ===========================================================================
// Kernel 2: channel mix. block = (corner 2, x 16, cg 16), c-tile of 4.
// grid 512. Weights packed (t even, t odd) per float4 -> b128 LDS reads.
// thread = (b 16, y 16). Y[b][c][kxi][ky][ri], same layout as Xf.
// (FROZEN at the round-2 configuration measured in the 165.7 run.)
// ===========================================================================
__global__ __launch_bounds__(256, 2) void k_mix(const float* __restrict__ Xf,
                                                const float* __restrict__ w0r,
                                                const float* __restrict__ w0i,
                                                const float* __restrict__ w1r,
                                                const float* __restrict__ w1i,
                                                float* __restrict__ Y) {
  __shared__ __attribute__((aligned(16))) float Wl[4 * 32 * 16 * 4]; // 32 KB
  const int bid = blockIdx.x;               // 0..511
  const int c2 = bid >> 8;
  const int x  = (bid >> 4) & 15;
  const int cg = bid & 15;
  const int c0 = cg * 4;
  const int kxi = c2 * 16 + x;
  const float* Wr_g = c2 ? w1r : w0r;
  const float* Wi_g = c2 ? w1i : w0i;
  const int tid = threadIdx.x;
  const int b = tid >> 4;
  const int y = tid & 15;

  // stage: 4096 complex; Wl f4[(c*32 + t/2)*16 + y] = (wr_e, wi_e, wr_o, wi_o)
  #pragma unroll
  for (int k = 0; k < 16; ++k) {
    int idx = tid + k * 256;                // 0..4095
    int y_ = idx & 15, t_ = (idx >> 4) & 63, c_ = idx >> 10;
    size_t ga = (((size_t)(c0 + c_) * 64 + t_) * 16 + x) * 16 + y_;
    int f2i = ((c_ * 32 + (t_ >> 1)) * 16 + y_) * 2 + (t_ & 1);
    *(float2*)&Wl[f2i * 2] = make_float2(Wr_g[ga], Wi_g[ga]);
  }
  __syncthreads();

  float aR[4] = {}, aI[4] = {};
  const float* xbase = Xf + ((size_t)b * 64) * 1024 + kxi * 32 + y * 2;
  for (int t8 = 0; t8 < 64; t8 += 8) {
    float2 xv[8];
    #pragma unroll
    for (int q = 0; q < 8; ++q)
      xv[q] = *(const float2*)&xbase[(size_t)(t8 + q) * 1024];
    #pragma unroll
    for (int p = 0; p < 4; ++p) {           // t2 pair index
      int t2 = (t8 >> 1) + p;
      float2 xe = xv[2 * p], xo = xv[2 * p + 1];
      #pragma unroll
      for (int cj = 0; cj < 4; ++cj) {
        float4 wv = *(const float4*)&Wl[((cj * 32 + t2) * 16 + y) * 4];
        aR[cj] = fmaf(xe.x, wv.x, aR[cj]); aR[cj] = fmaf(-xe.y, wv.y, aR[cj]);
        aI[cj] = fmaf(xe.x, wv.y, aI[cj]); aI[cj] = fmaf(xe.y, wv.x, aI[cj]);
        aR[cj] = fmaf(xo.x, wv.z, aR[cj]); aR[cj] = fmaf(-xo.y, wv.w, aR[cj]);
        aI[cj] = fmaf(xo.x, wv.w, aI[cj]); aI[cj] = fmaf(xo.y, wv.z, aI[cj]);
      }
    }
  }
  #pragma unroll
  for (int cj = 0; cj < 4; ++cj) {
    size_t ya = ((size_t)(b * 64 + c0 + cj)) * 1024 + kxi * 32 + y * 2;
    *(float2*)&Y[ya] = make_float2(aR[cj], aI[cj]);
  }
}

// ===========================================================================
// Kernel 3: per (b,c) plane inverse.  (FROZEN since round 2)
// Phase A: thread = (g 0..3 ky-quad, h2 0..63); handles h in {h2, h2+64}
//   via sign (-1)^kx on the shared twiddle. Stores Mt f4-packed with XOR
//   swizzle: f4idx = h*8 + (j ^ (h&7))  (write-conflict-free).
// Phase B: thread = (hp 0..7, w2 0..31); 16 h each, outputs w2, w2+32,
//   w2+64, w2+96. The w2+32 twiddles are the i^k register rotation of w2's
//   C/S; the +64 fold uses ky parity.
// ===========================================================================
__global__ __launch_bounds__(256, 4) void k_inv(const float* __restrict__ Y,
                                                float* __restrict__ out) {
  __shared__ __attribute__((aligned(16))) float Yl[1024];
  __shared__ __attribute__((aligned(16))) float Mt[128 * 16 * 2];  // 16 KB
  const int plane = blockIdx.x;
  const int tid = threadIdx.x;
  *(float4*)&Yl[tid * 4] = *(const float4*)&Y[(size_t)plane * 1024 + tid * 4];
  __syncthreads();

  // ---- phase A ----
  {
    const int g = tid >> 6;          // ky quad: ky = 4g..4g+3 (wave-uniform)
    const int h2 = tid & 63;
    float zr[2][4] = {}, zi[2][4] = {};   // [h-sel][ky j]
    float uw, uwi;                   // U = e^{+2pi i h2/128}
    __sincosf(PI2 * (float)h2 / 128.f, &uwi, &uw);
    const float4* Yl4 = (const float4*)Yl;
    float Tr = 1.f, Ti = 0.f;
    #pragma unroll 2
    for (int kxi = 0; kxi < 16; ++kxi) {
      float sgn = (kxi & 1) ? -1.f : 1.f;    // (-1)^kx for h2+64
      #pragma unroll
      for (int q = 0; q < 2; ++q) {
        float4 p = Yl4[kxi * 8 + g * 2 + q];
        float cr0 = p.x * Tr - p.y * Ti, ci0 = p.x * Ti + p.y * Tr;
        float cr1 = p.z * Tr - p.w * Ti, ci1 = p.z * Ti + p.w * Tr;
        zr[0][2*q]   += cr0; zi[0][2*q]   += ci0;
        zr[0][2*q+1] += cr1; zi[0][2*q+1] += ci1;
        zr[1][2*q]   = fmaf(sgn, cr0, zr[1][2*q]);   zi[1][2*q]   = fmaf(sgn, ci0, zi[1][2*q]);
        zr[1][2*q+1] = fmaf(sgn, cr1, zr[1][2*q+1]); zi[1][2*q+1] = fmaf(sgn, ci1, zi[1][2*q+1]);
      }
      float nr = Tr * uw - Ti * uwi, ni = Tr * uwi + Ti * uw;
      Tr = nr; Ti = ni;
    }
    __sincosf(PI2 * (float)((112 * h2) & 127) / 128.f, &Ti, &Tr);
    #pragma unroll 2
    for (int kxi = 16; kxi < 32; ++kxi) {
      float sgn = (kxi & 1) ? -1.f : 1.f;
      #pragma unroll
      for (int q = 0; q < 2; ++q) {
        float4 p = Yl4[kxi * 8 + g * 2 + q];
        float cr0 = p.x * Tr - p.y * Ti, ci0 = p.x * Ti + p.y * Tr;
        float cr1 = p.z * Tr - p.w * Ti, ci1 = p.z * Ti + p.w * Tr;
        zr[0][2*q]   += cr0; zi[0][2*q]   += ci0;
        zr[0][2*q+1] += cr1; zi[0][2*q+1] += ci1;
        zr[1][2*q]   = fmaf(sgn, cr0, zr[1][2*q]);   zi[1][2*q]   = fmaf(sgn, ci0, zi[1][2*q]);
        zr[1][2*q+1] = fmaf(sgn, cr1, zr[1][2*q+1]); zi[1][2*q+1] = fmaf(sgn, ci1, zi[1][2*q+1]);
      }
      float nr = Tr * uw - Ti * uwi, ni = Tr * uwi + Ti * uw;
      Tr = nr; Ti = ni;
    }
    #pragma unroll
    for (int hs = 0; hs < 2; ++hs) {
      int h = h2 + hs * 64;
      #pragma unroll
      for (int q = 0; q < 2; ++q) {
        int ky0 = g * 4 + 2 * q;
        float f0 = (ky0 == 0) ? 1.f : 2.f;
        float4 v = make_float4(f0 * zr[hs][2*q],   -f0 * zi[hs][2*q],
                               2.f * zr[hs][2*q+1], -2.f * zi[hs][2*q+1]);
        int f4i = h * 8 + ((g * 2 + q) ^ (h & 7));
        *(float4*)&Mt[f4i * 4] = v;
      }
    }
  }
  __syncthreads();

  // ---- phase B ----
  {
    const int hp = tid >> 5;        // 0..7
    const int w2 = tid & 31;        // 0..31
    float C[16], S[16];
    {
      float cw, sw;
      __sincosf(PI2 * (float)w2 / 128.f, &sw, &cw);
      C[0] = 1.f; S[0] = 0.f;
      #pragma unroll
      for (int k = 1; k < 16; ++k) {
        C[k] = C[k - 1] * cw - S[k - 1] * sw;
        S[k] = C[k - 1] * sw + S[k - 1] * cw;
      }
    }
    float* op = out + (size_t)plane * (128 * 128);
    const float4* Mt4 = (const float4*)Mt;
    #pragma unroll 2
    for (int hj = 0; hj < 16; ++hj) {
      int h = hp * 16 + hj;
      float e = 0.f, o = 0.f, e2 = 0.f, o2 = 0.f;
      #pragma unroll
      for (int j = 0; j < 8; ++j) {
        float4 m = Mt4[h * 8 + (j ^ (h & 7))];   // (Mc,Ms) ky=2j | ky=2j+1
        int k0 = 2 * j, k1 = 2 * j + 1;
        e = fmaf(m.x, C[k0], e); e = fmaf(m.y, S[k0], e);
        o = fmaf(m.z, C[k1], o); o = fmaf(m.w, S[k1], o);
        // w2+32: cos(th+pi k/2), sin(th+pi k/2) rotations
        if ((k0 & 2) == 0) { e2 = fmaf(m.x, C[k0], e2); e2 = fmaf(m.y, S[k0], e2); }
        else               { e2 = fmaf(-m.x, C[k0], e2); e2 = fmaf(-m.y, S[k0], e2); }
        if ((k1 & 2) == 0) { o2 = fmaf(m.w, C[k1], o2); o2 = fmaf(-m.z, S[k1], o2); }
        else               { o2 = fmaf(-m.w, C[k1], o2); o2 = fmaf(m.z, S[k1], o2); }
      }
      op[h * 128 + w2]      = e + o;
      op[h * 128 + w2 + 64] = e - o;
      op[h * 128 + w2 + 32] = e2 + o2;
      op[h * 128 + w2 + 96] = e2 - o2;
    }
  }
}

extern "C" void kernel_launch(void* const* d_in, const int* in_sizes, int n_in,
                              void* d_out, int out_size, void* d_ws, size_t ws_size,
                              hipStream_t stream) {
  const float* X   = (const float*)d_in[0];
  const float* w0r = (const float*)d_in[1];
  const float* w0i = (const float*)d_in[2];
  const float* w1r = (const float*)d_in[3];
  const float* w1i = (const float*)d_in[4];
  float* outp = (float*)d_out;
  float* Xf = (float*)d_ws;                  // 4 MB
  float* Yw = (float*)d_ws + (1u << 20);     // 4 MB
  k_fwd<<<1024, 256, 0, stream>>>(X, Xf);
  k_mix<<<512, 256, 0, stream>>>(Xf, w0r, w0i, w1r, w1i, Yw);
  k_inv<<<1024, 256, 0, stream>>>(Yw, outp);
}